// Round 5
// baseline (814.143 us; speedup 1.0000x reference)
//
#include <hip/hip_runtime.h>
#include <hip/hip_bf16.h>
#include <stdint.h>

typedef __bf16 bf16_t;
typedef bf16_t bf16x8 __attribute__((ext_vector_type(8)));
typedef bf16_t bf16x4 __attribute__((ext_vector_type(4)));
typedef bf16_t bf16x2 __attribute__((ext_vector_type(2)));
typedef float f32x4 __attribute__((ext_vector_type(4)));
typedef uint32_t u32x4 __attribute__((ext_vector_type(4)));

// ---- workspace layout ----
// 0      : wq  bf16 [256][256]  (pre-scaled by 1/sqrt(32))
// 131072 : wkv bf16 [512][256]
// 393216 : wo  bf16 [256][256]
// 524288 : bias8 f32 [8][64][64]   ([h][q][k])
#define WS_WKV_OFF 65536   // elems
#define WS_WO_OFF  196608  // elems
#define WS_B8_OFF  524288  // bytes
#define QSCALE 0.17677669529663687f

__global__ __launch_bounds__(256) void prep_kernel(
    const float* __restrict__ wq, const float* __restrict__ wkv,
    const float* __restrict__ wo, const float* __restrict__ bt,
    const int* __restrict__ rp,
    bf16_t* __restrict__ wsq, bf16_t* __restrict__ wskv,
    bf16_t* __restrict__ wso, float* __restrict__ bias8) {
  int t = blockIdx.x * 256 + threadIdx.x;
  if (t < 65536)  wsq[t]  = (bf16_t)(wq[t] * QSCALE);
  if (t < 131072) wskv[t] = (bf16_t)wkv[t];
  if (t < 65536)  wso[t]  = (bf16_t)wo[t];
  if (t < 4096) {
    int idx = rp[t];
#pragma unroll
    for (int h = 0; h < 8; ++h) bias8[h * 4096 + t] = bt[idx * 8 + h];
  }
}

// 4-lane-group register transpose: build an MFMA A/B-frag (lane holds
// M[k=8*lgrp+j][n=16t+lrow], j=0..7) from packed C-frag pairs.
__device__ __forceinline__ bf16x8 xpose_frag(uint32_t e0, uint32_t e1,
                                             uint32_t o0, uint32_t o1,
                                             int ad0, int ad1, bool hi) {
  uint32_t v0e = (uint32_t)__builtin_amdgcn_ds_bpermute(ad0, (int)e0);
  uint32_t v0o = (uint32_t)__builtin_amdgcn_ds_bpermute(ad0, (int)o0);
  uint32_t v1e = (uint32_t)__builtin_amdgcn_ds_bpermute(ad0, (int)e1);
  uint32_t v1o = (uint32_t)__builtin_amdgcn_ds_bpermute(ad0, (int)o1);
  uint32_t v2e = (uint32_t)__builtin_amdgcn_ds_bpermute(ad1, (int)e0);
  uint32_t v2o = (uint32_t)__builtin_amdgcn_ds_bpermute(ad1, (int)o0);
  uint32_t v3e = (uint32_t)__builtin_amdgcn_ds_bpermute(ad1, (int)e1);
  uint32_t v3o = (uint32_t)__builtin_amdgcn_ds_bpermute(ad1, (int)o1);
  u32x4 r;
  r.x = hi ? v0o : v0e;
  r.y = hi ? v1o : v1e;
  r.z = hi ? v2o : v2e;
  r.w = hi ? v3o : v3e;
  return __builtin_bit_cast(bf16x8, r);
}

__device__ __forceinline__ uint32_t pk2(float a, float b) {
  bf16x2 t = {(bf16_t)a, (bf16_t)b};
  return __builtin_bit_cast(uint32_t, t);
}

// LDS (bf16 elems):
//   xs [64][264] @ 0 (16896 el, 33792 B) -- overlaid by O [64][264] in ph 3-5
//   Vt per head  @ 16896 + h*2304: [32 d][72 n] (2304 el) -- wave-private
// total 35328 el = 70656 B -> 2 blocks/CU by LDS.
__global__ __launch_bounds__(512, 4) void win_attn_kernel(
    const float* __restrict__ x, const float* __restrict__ mask,
    const float* __restrict__ bq, const float* __restrict__ bkv,
    const float* __restrict__ bo,
    const bf16_t* __restrict__ wsq, const bf16_t* __restrict__ wskv,
    const bf16_t* __restrict__ wso, const float* __restrict__ bias8,
    float* __restrict__ out) {
  __shared__ bf16_t lds[35328];
  const int b    = blockIdx.x;
  const int tid  = threadIdx.x;
  const int h    = tid >> 6;     // one wave per head
  const int lane = tid & 63;
  const int lrow = lane & 15;
  const int lgrp = lane >> 4;
  const bool hi  = (lgrp & 2) != 0;
  const int ad0  = ((((2 * lgrp) & 3) << 4) + lrow) << 2;
  const int ad1  = ((((2 * lgrp + 1) & 3) << 4) + lrow) << 2;
  const f32x4 zf = {0.f, 0.f, 0.f, 0.f};

  // ---------- phase 1: stage x (f32) -> bf16 LDS xs[64][264] ----------
  {
    const float4* xv = (const float4*)(x + (size_t)b * 16384);
#pragma unroll
    for (int j = 0; j < 8; ++j) {
      int i4 = j * 512 + tid;
      float4 v = xv[i4];
      int e = i4 * 4;
      int r = e >> 8, c = e & 255;
      bf16x4 w = {(bf16_t)v.x, (bf16_t)v.y, (bf16_t)v.z, (bf16_t)v.w};
      *(bf16x4*)(lds + r * 264 + c) = w;
    }
  }
  __syncthreads();

  bf16_t* ldsVt = lds + 16896 + h * 2304;   // [32][72], wave-private

  // ---------- phase 2a: Qt[d][n] then Kt[d][n] (two passes, low pressure) ----------
  bf16x8 qb[4], ka[4];
  {
    const bf16_t* WQh = wsq + h * 32 * 256;
    f32x4 aq[2][4];
#pragma unroll
    for (int tm = 0; tm < 2; ++tm)
#pragma unroll
      for (int tn = 0; tn < 4; ++tn) aq[tm][tn] = zf;
#pragma unroll
    for (int ks = 0; ks < 8; ++ks) {
      bf16x8 xb[4];
#pragma unroll
      for (int tn = 0; tn < 4; ++tn)
        xb[tn] = *(const bf16x8*)(lds + (tn * 16 + lrow) * 264 + ks * 32 + lgrp * 8);
      bf16x8 wqf[2];
#pragma unroll
      for (int tm = 0; tm < 2; ++tm)
        wqf[tm] = *(const bf16x8*)(WQh + (tm * 16 + lrow) * 256 + ks * 32 + lgrp * 8);
#pragma unroll
      for (int tm = 0; tm < 2; ++tm)
#pragma unroll
        for (int tn = 0; tn < 4; ++tn)
          aq[tm][tn] = __builtin_amdgcn_mfma_f32_16x16x32_bf16(wqf[tm], xb[tn], aq[tm][tn], 0, 0, 0);
    }
    uint32_t pkq[2][4][2];
#pragma unroll
    for (int tm = 0; tm < 2; ++tm) {
      float4 b4 = *(const float4*)(bq + h * 32 + tm * 16 + lgrp * 4);
      float bqa[4] = {b4.x * QSCALE, b4.y * QSCALE, b4.z * QSCALE, b4.w * QSCALE};
#pragma unroll
      for (int tn = 0; tn < 4; ++tn)
#pragma unroll
        for (int pr = 0; pr < 2; ++pr)
          pkq[tm][tn][pr] = pk2(aq[tm][tn][2 * pr] + bqa[2 * pr],
                                aq[tm][tn][2 * pr + 1] + bqa[2 * pr + 1]);
    }
#pragma unroll
    for (int t = 0; t < 4; ++t)
      qb[t] = xpose_frag(pkq[0][t][0], pkq[0][t][1], pkq[1][t][0], pkq[1][t][1], ad0, ad1, hi);
  }
  {
    const bf16_t* WKh = wskv + h * 32 * 256;
    f32x4 akk[2][4];
#pragma unroll
    for (int tm = 0; tm < 2; ++tm)
#pragma unroll
      for (int tn = 0; tn < 4; ++tn) akk[tm][tn] = zf;
#pragma unroll
    for (int ks = 0; ks < 8; ++ks) {
      bf16x8 xb[4];
#pragma unroll
      for (int tn = 0; tn < 4; ++tn)
        xb[tn] = *(const bf16x8*)(lds + (tn * 16 + lrow) * 264 + ks * 32 + lgrp * 8);
      bf16x8 wkf[2];
#pragma unroll
      for (int tm = 0; tm < 2; ++tm)
        wkf[tm] = *(const bf16x8*)(WKh + (tm * 16 + lrow) * 256 + ks * 32 + lgrp * 8);
#pragma unroll
      for (int tm = 0; tm < 2; ++tm)
#pragma unroll
        for (int tn = 0; tn < 4; ++tn)
          akk[tm][tn] = __builtin_amdgcn_mfma_f32_16x16x32_bf16(wkf[tm], xb[tn], akk[tm][tn], 0, 0, 0);
    }
    uint32_t pkk[2][4][2];
#pragma unroll
    for (int tm = 0; tm < 2; ++tm) {
      float4 k4 = *(const float4*)(bkv + h * 32 + tm * 16 + lgrp * 4);
      float bka[4] = {k4.x, k4.y, k4.z, k4.w};
#pragma unroll
      for (int tn = 0; tn < 4; ++tn)
#pragma unroll
        for (int pr = 0; pr < 2; ++pr)
          pkk[tm][tn][pr] = pk2(akk[tm][tn][2 * pr] + bka[2 * pr],
                                akk[tm][tn][2 * pr + 1] + bka[2 * pr + 1]);
    }
#pragma unroll
    for (int t = 0; t < 4; ++t)
      ka[t] = xpose_frag(pkk[0][t][0], pkk[0][t][1], pkk[1][t][0], pkk[1][t][1], ad0, ad1, hi);
  }

  // ---------- phase 2b: V[n][d] -> LDS Vt[d][n] (wave-private, no xpose) ----------
  {
    const bf16_t* WVh = wskv + (256 + h * 32) * 256;
    f32x4 av[4][2];
#pragma unroll
    for (int tm = 0; tm < 4; ++tm)
#pragma unroll
      for (int tn = 0; tn < 2; ++tn) av[tm][tn] = zf;
#pragma unroll
    for (int ks = 0; ks < 8; ++ks) {
      bf16x8 xa[4];
#pragma unroll
      for (int tm = 0; tm < 4; ++tm)
        xa[tm] = *(const bf16x8*)(lds + (tm * 16 + lrow) * 264 + ks * 32 + lgrp * 8);
      bf16x8 wvf[2];
#pragma unroll
      for (int tn = 0; tn < 2; ++tn)
        wvf[tn] = *(const bf16x8*)(WVh + (tn * 16 + lrow) * 256 + ks * 32 + lgrp * 8);
#pragma unroll
      for (int tm = 0; tm < 4; ++tm)
#pragma unroll
        for (int tn = 0; tn < 2; ++tn)
          av[tm][tn] = __builtin_amdgcn_mfma_f32_16x16x32_bf16(xa[tm], wvf[tn], av[tm][tn], 0, 0, 0);
    }
    float bv0 = bkv[256 + h * 32 + lrow];
    float bv1 = bkv[256 + h * 32 + 16 + lrow];
    // C-frag: row = token n = 16tm+4lgrp+r, col = d = 16tn+lrow.
    // Store transposed: Vt[d][n], 4 consecutive n per lane -> bf16x4.
#pragma unroll
    for (int tm = 0; tm < 4; ++tm)
#pragma unroll
      for (int tn = 0; tn < 2; ++tn) {
        float bv = tn ? bv1 : bv0;
        bf16x4 vv;
#pragma unroll
        for (int r = 0; r < 4; ++r) vv[r] = (bf16_t)(av[tm][tn][r] + bv);
        *(bf16x4*)(ldsVt + (tn * 16 + lrow) * 72 + tm * 16 + lgrp * 4) = vv;
      }
  }

  // All xs reads are done; after this barrier the O tile overlays xs.
  __syncthreads();

  // ---------- phase 3+4: per q-tile: St = K.Qt, softmax (no max-sub), O = P.V ----------
  const float* maskw = mask + (size_t)(b & 1023) * 4096;
  const float* biash = bias8 + h * 4096;
#pragma unroll
  for (int qt = 0; qt < 4; ++qt) {
    f32x4 st[4];
#pragma unroll
    for (int tm = 0; tm < 4; ++tm)
      st[tm] = __builtin_amdgcn_mfma_f32_16x16x32_bf16(ka[tm], qb[qt], zf, 0, 0, 0);
    int q = qt * 16 + lrow;
    float sm = 0.f;
#pragma unroll
    for (int tm = 0; tm < 4; ++tm) {
      int kb = tm * 16 + lgrp * 4;
      float4 mb = *(const float4*)(maskw + q * 64 + kb);
      float4 bb = *(const float4*)(biash + q * 64 + kb);
#pragma unroll
      for (int r = 0; r < 4; ++r) {
        float madd = (r == 0) ? (mb.x + bb.x) : (r == 1) ? (mb.y + bb.y)
                   : (r == 2) ? (mb.z + bb.z) : (mb.w + bb.w);
        float p = __expf(st[tm][r] + madd);   // inputs bounded (|s|<~10): no max-sub
        st[tm][r] = p;
        sm += p;
      }
    }
    sm += __shfl_xor(sm, 16);
    sm += __shfl_xor(sm, 32);
    float rs = 1.0f / sm;
    uint32_t ppk[4][2];
#pragma unroll
    for (int tm = 0; tm < 4; ++tm) {
      ppk[tm][0] = pk2(st[tm][0] * rs, st[tm][1] * rs);
      ppk[tm][1] = pk2(st[tm][2] * rs, st[tm][3] * rs);
    }
    bf16x8 paf[2];
#pragma unroll
    for (int kf = 0; kf < 2; ++kf)
      paf[kf] = xpose_frag(ppk[2 * kf][0], ppk[2 * kf][1],
                           ppk[2 * kf + 1][0], ppk[2 * kf + 1][1], ad0, ad1, hi);
    f32x4 o[2] = {zf, zf};
#pragma unroll
    for (int dt = 0; dt < 2; ++dt)
#pragma unroll
      for (int kf = 0; kf < 2; ++kf) {
        bf16x8 vf = *(const bf16x8*)(ldsVt + (dt * 16 + lrow) * 72 + kf * 32 + lgrp * 8);
        o[dt] = __builtin_amdgcn_mfma_f32_16x16x32_bf16(paf[kf], vf, o[dt], 0, 0, 0);
      }
    // write O rows for this q-tile (O overlays xs; barrier above protects)
#pragma unroll
    for (int dt = 0; dt < 2; ++dt)
#pragma unroll
      for (int r = 0; r < 4; ++r)
        lds[(qt * 16 + lgrp * 4 + r) * 264 + h * 32 + dt * 16 + lrow] = (bf16_t)o[dt][r];
  }
  __syncthreads();

  // ---------- phase 5: out = O @ w_o^T + b_o ----------
  const int nb = h * 32;
  f32x4 oc[4][2];
#pragma unroll
  for (int tm = 0; tm < 4; ++tm)
#pragma unroll
    for (int tn = 0; tn < 2; ++tn) oc[tm][tn] = zf;
#pragma unroll
  for (int ks = 0; ks < 8; ++ks) {
    bf16x8 ao[4];
#pragma unroll
    for (int tm = 0; tm < 4; ++tm)
      ao[tm] = *(const bf16x8*)(lds + (tm * 16 + lrow) * 264 + ks * 32 + lgrp * 8);
    bf16x8 bw[2];
#pragma unroll
    for (int tn = 0; tn < 2; ++tn)
      bw[tn] = *(const bf16x8*)(wso + (nb + tn * 16 + lrow) * 256 + ks * 32 + lgrp * 8);
#pragma unroll
    for (int tm = 0; tm < 4; ++tm)
#pragma unroll
      for (int tn = 0; tn < 2; ++tn)
        oc[tm][tn] = __builtin_amdgcn_mfma_f32_16x16x32_bf16(ao[tm], bw[tn], oc[tm][tn], 0, 0, 0);
  }
  float* outw = out + (size_t)b * 16384;
#pragma unroll
  for (int tn = 0; tn < 2; ++tn) {
    float bov = bo[nb + tn * 16 + lrow];
#pragma unroll
    for (int tm = 0; tm < 4; ++tm)
#pragma unroll
      for (int r = 0; r < 4; ++r)
        outw[(tm * 16 + lgrp * 4 + r) * 256 + nb + tn * 16 + lrow] = oc[tm][tn][r] + bov;
  }
}

extern "C" void kernel_launch(void* const* d_in, const int* in_sizes, int n_in,
                              void* d_out, int out_size, void* d_ws, size_t ws_size,
                              hipStream_t stream) {
  const float* x    = (const float*)d_in[0];
  const float* mask = (const float*)d_in[1];
  const float* wq   = (const float*)d_in[2];
  const float* bq   = (const float*)d_in[3];
  const float* wkv  = (const float*)d_in[4];
  const float* bkv  = (const float*)d_in[5];
  const float* bt   = (const float*)d_in[6];
  const float* wo   = (const float*)d_in[7];
  const float* bo   = (const float*)d_in[8];
  const int*   rp   = (const int*)d_in[9];
  float* out = (float*)d_out;

  bf16_t* wsq  = (bf16_t*)d_ws;
  bf16_t* wskv = wsq + WS_WKV_OFF;
  bf16_t* wso  = wsq + WS_WO_OFF;
  float*  bias8 = (float*)((char*)d_ws + WS_B8_OFF);

  prep_kernel<<<512, 256, 0, stream>>>(wq, wkv, wo, bt, rp, wsq, wskv, wso, bias8);

  win_attn_kernel<<<4096, 512, 0, stream>>>(
      x, mask, bq, bkv, bo, wsq, wskv, wso, bias8, out);
}

// Round 6
// 497.736 us; speedup vs baseline: 1.6357x; 1.6357x over previous
//
#include <hip/hip_runtime.h>
#include <hip/hip_bf16.h>
#include <stdint.h>

typedef __bf16 bf16_t;
typedef bf16_t bf16x8 __attribute__((ext_vector_type(8)));
typedef bf16_t bf16x4 __attribute__((ext_vector_type(4)));
typedef bf16_t bf16x2 __attribute__((ext_vector_type(2)));
typedef float f32x4 __attribute__((ext_vector_type(4)));
typedef uint32_t u32x4 __attribute__((ext_vector_type(4)));

// ---- workspace layout ----
// 0      : wq  bf16 [256][256]  (pre-scaled by 1/sqrt(32))
// 131072 : wkv bf16 [512][256]
// 393216 : wo  bf16 [256][256]
// 524288 : bias8 f32 [8][64][64]   ([h][q][k])
#define WS_WKV_OFF 65536   // elems
#define WS_WO_OFF  196608  // elems
#define WS_B8_OFF  524288  // bytes
#define QSCALE 0.17677669529663687f

__global__ __launch_bounds__(256) void prep_kernel(
    const float* __restrict__ wq, const float* __restrict__ wkv,
    const float* __restrict__ wo, const float* __restrict__ bt,
    const int* __restrict__ rp,
    bf16_t* __restrict__ wsq, bf16_t* __restrict__ wskv,
    bf16_t* __restrict__ wso, float* __restrict__ bias8) {
  int t = blockIdx.x * 256 + threadIdx.x;
  if (t < 65536)  wsq[t]  = (bf16_t)(wq[t] * QSCALE);
  if (t < 131072) wskv[t] = (bf16_t)wkv[t];
  if (t < 65536)  wso[t]  = (bf16_t)wo[t];
  if (t < 4096) {
    int idx = rp[t];
#pragma unroll
    for (int h = 0; h < 8; ++h) bias8[h * 4096 + t] = bt[idx * 8 + h];
  }
}

// 4-lane-group register transpose: build an MFMA A/B-frag (lane holds
// M[k=8*lgrp+j][n=16t+lrow], j=0..7) from packed C-frag pairs.
__device__ __forceinline__ bf16x8 xpose_frag(uint32_t e0, uint32_t e1,
                                             uint32_t o0, uint32_t o1,
                                             int ad0, int ad1, bool hi) {
  uint32_t v0e = (uint32_t)__builtin_amdgcn_ds_bpermute(ad0, (int)e0);
  uint32_t v0o = (uint32_t)__builtin_amdgcn_ds_bpermute(ad0, (int)o0);
  uint32_t v1e = (uint32_t)__builtin_amdgcn_ds_bpermute(ad0, (int)e1);
  uint32_t v1o = (uint32_t)__builtin_amdgcn_ds_bpermute(ad0, (int)o1);
  uint32_t v2e = (uint32_t)__builtin_amdgcn_ds_bpermute(ad1, (int)e0);
  uint32_t v2o = (uint32_t)__builtin_amdgcn_ds_bpermute(ad1, (int)o0);
  uint32_t v3e = (uint32_t)__builtin_amdgcn_ds_bpermute(ad1, (int)e1);
  uint32_t v3o = (uint32_t)__builtin_amdgcn_ds_bpermute(ad1, (int)o1);
  u32x4 r;
  r.x = hi ? v0o : v0e;
  r.y = hi ? v1o : v1e;
  r.z = hi ? v2o : v2e;
  r.w = hi ? v3o : v3e;
  return __builtin_bit_cast(bf16x8, r);
}

__device__ __forceinline__ uint32_t pk2(float a, float b) {
  bf16x2 t = {(bf16_t)a, (bf16_t)b};
  return __builtin_bit_cast(uint32_t, t);
}

// LDS (bf16 elems):
//   xs [64][264] @ 0 (16896 el, 33792 B) -- overlaid by O [64][264] in ph 3-5
//   Vt per head  @ 16896 + h*2304: [32 d][72 n] (2304 el) -- wave-private
// total 35328 el = 70656 B -> 2 blocks/CU by LDS.
__global__ __launch_bounds__(512, 2) void win_attn_kernel(
    const float* __restrict__ x, const float* __restrict__ mask,
    const float* __restrict__ bq, const float* __restrict__ bkv,
    const float* __restrict__ bo,
    const bf16_t* __restrict__ wsq, const bf16_t* __restrict__ wskv,
    const bf16_t* __restrict__ wso, const float* __restrict__ bias8,
    float* __restrict__ out) {
  __shared__ bf16_t lds[35328];
  const int b    = blockIdx.x;
  const int tid  = threadIdx.x;
  const int h    = tid >> 6;     // one wave per head
  const int lane = tid & 63;
  const int lrow = lane & 15;
  const int lgrp = lane >> 4;
  const bool hi  = (lgrp & 2) != 0;
  const int ad0  = ((((2 * lgrp) & 3) << 4) + lrow) << 2;
  const int ad1  = ((((2 * lgrp + 1) & 3) << 4) + lrow) << 2;
  const f32x4 zf = {0.f, 0.f, 0.f, 0.f};

  // ---------- phase 1: stage x (f32) -> bf16 LDS xs[64][264] ----------
  {
    const float4* xv = (const float4*)(x + (size_t)b * 16384);
#pragma unroll
    for (int j = 0; j < 8; ++j) {
      int i4 = j * 512 + tid;
      float4 v = xv[i4];
      int e = i4 * 4;
      int r = e >> 8, c = e & 255;
      bf16x4 w = {(bf16_t)v.x, (bf16_t)v.y, (bf16_t)v.z, (bf16_t)v.w};
      *(bf16x4*)(lds + r * 264 + c) = w;
    }
  }
  __syncthreads();

  bf16_t* ldsVt = lds + 16896 + h * 2304;   // [32][72], wave-private

  // ---------- phase 2a: V[n][d] -> LDS Vt[d][n] (FIRST: no frags live) ----------
  {
    const bf16_t* WVh = wskv + (256 + h * 32) * 256;
    f32x4 av[4][2];
#pragma unroll
    for (int tm = 0; tm < 4; ++tm)
#pragma unroll
      for (int tn = 0; tn < 2; ++tn) av[tm][tn] = zf;
#pragma unroll
    for (int ks = 0; ks < 8; ++ks) {
      bf16x8 xa[4];
#pragma unroll
      for (int tm = 0; tm < 4; ++tm)
        xa[tm] = *(const bf16x8*)(lds + (tm * 16 + lrow) * 264 + ks * 32 + lgrp * 8);
      bf16x8 wvf[2];
#pragma unroll
      for (int tn = 0; tn < 2; ++tn)
        wvf[tn] = *(const bf16x8*)(WVh + (tn * 16 + lrow) * 256 + ks * 32 + lgrp * 8);
#pragma unroll
      for (int tm = 0; tm < 4; ++tm)
#pragma unroll
        for (int tn = 0; tn < 2; ++tn)
          av[tm][tn] = __builtin_amdgcn_mfma_f32_16x16x32_bf16(xa[tm], wvf[tn], av[tm][tn], 0, 0, 0);
    }
    float bv0 = bkv[256 + h * 32 + lrow];
    float bv1 = bkv[256 + h * 32 + 16 + lrow];
    // C-frag: row = token n = 16tm+4lgrp+r, col = d = 16tn+lrow.
    // Store transposed: Vt[d][n], 4 consecutive n per lane -> bf16x4.
#pragma unroll
    for (int tm = 0; tm < 4; ++tm)
#pragma unroll
      for (int tn = 0; tn < 2; ++tn) {
        float bv = tn ? bv1 : bv0;
        bf16x4 vv;
#pragma unroll
        for (int r = 0; r < 4; ++r) vv[r] = (bf16_t)(av[tm][tn][r] + bv);
        *(bf16x4*)(ldsVt + (tn * 16 + lrow) * 72 + tm * 16 + lgrp * 4) = vv;
      }
  }

  // ---------- phase 2b: Qt[d][n] then Kt[d][n] (two passes, low pressure) ----------
  bf16x8 qb[4], ka[4];
  {
    const bf16_t* WQh = wsq + h * 32 * 256;
    f32x4 aq[2][4];
#pragma unroll
    for (int tm = 0; tm < 2; ++tm)
#pragma unroll
      for (int tn = 0; tn < 4; ++tn) aq[tm][tn] = zf;
#pragma unroll
    for (int ks = 0; ks < 8; ++ks) {
      bf16x8 xb[4];
#pragma unroll
      for (int tn = 0; tn < 4; ++tn)
        xb[tn] = *(const bf16x8*)(lds + (tn * 16 + lrow) * 264 + ks * 32 + lgrp * 8);
      bf16x8 wqf[2];
#pragma unroll
      for (int tm = 0; tm < 2; ++tm)
        wqf[tm] = *(const bf16x8*)(WQh + (tm * 16 + lrow) * 256 + ks * 32 + lgrp * 8);
#pragma unroll
      for (int tm = 0; tm < 2; ++tm)
#pragma unroll
        for (int tn = 0; tn < 4; ++tn)
          aq[tm][tn] = __builtin_amdgcn_mfma_f32_16x16x32_bf16(wqf[tm], xb[tn], aq[tm][tn], 0, 0, 0);
    }
    uint32_t pkq[2][4][2];
#pragma unroll
    for (int tm = 0; tm < 2; ++tm) {
      float4 b4 = *(const float4*)(bq + h * 32 + tm * 16 + lgrp * 4);
      float bqa[4] = {b4.x * QSCALE, b4.y * QSCALE, b4.z * QSCALE, b4.w * QSCALE};
#pragma unroll
      for (int tn = 0; tn < 4; ++tn)
#pragma unroll
        for (int pr = 0; pr < 2; ++pr)
          pkq[tm][tn][pr] = pk2(aq[tm][tn][2 * pr] + bqa[2 * pr],
                                aq[tm][tn][2 * pr + 1] + bqa[2 * pr + 1]);
    }
#pragma unroll
    for (int t = 0; t < 4; ++t)
      qb[t] = xpose_frag(pkq[0][t][0], pkq[0][t][1], pkq[1][t][0], pkq[1][t][1], ad0, ad1, hi);
  }
  {
    const bf16_t* WKh = wskv + h * 32 * 256;
    f32x4 akk[2][4];
#pragma unroll
    for (int tm = 0; tm < 2; ++tm)
#pragma unroll
      for (int tn = 0; tn < 4; ++tn) akk[tm][tn] = zf;
#pragma unroll
    for (int ks = 0; ks < 8; ++ks) {
      bf16x8 xb[4];
#pragma unroll
      for (int tn = 0; tn < 4; ++tn)
        xb[tn] = *(const bf16x8*)(lds + (tn * 16 + lrow) * 264 + ks * 32 + lgrp * 8);
      bf16x8 wkf[2];
#pragma unroll
      for (int tm = 0; tm < 2; ++tm)
        wkf[tm] = *(const bf16x8*)(WKh + (tm * 16 + lrow) * 256 + ks * 32 + lgrp * 8);
#pragma unroll
      for (int tm = 0; tm < 2; ++tm)
#pragma unroll
        for (int tn = 0; tn < 4; ++tn)
          akk[tm][tn] = __builtin_amdgcn_mfma_f32_16x16x32_bf16(wkf[tm], xb[tn], akk[tm][tn], 0, 0, 0);
    }
    uint32_t pkk[2][4][2];
#pragma unroll
    for (int tm = 0; tm < 2; ++tm) {
      float4 k4 = *(const float4*)(bkv + h * 32 + tm * 16 + lgrp * 4);
      float bka[4] = {k4.x, k4.y, k4.z, k4.w};
#pragma unroll
      for (int tn = 0; tn < 4; ++tn)
#pragma unroll
        for (int pr = 0; pr < 2; ++pr)
          pkk[tm][tn][pr] = pk2(akk[tm][tn][2 * pr] + bka[2 * pr],
                                akk[tm][tn][2 * pr + 1] + bka[2 * pr + 1]);
    }
#pragma unroll
    for (int t = 0; t < 4; ++t)
      ka[t] = xpose_frag(pkk[0][t][0], pkk[0][t][1], pkk[1][t][0], pkk[1][t][1], ad0, ad1, hi);
  }

  // All xs reads are done; after this barrier the O tile overlays xs.
  __syncthreads();

  // ---------- phase 3+4: per q-tile: St = K.Qt, softmax (no max-sub), O = P.V ----------
  const float* maskw = mask + (size_t)(b & 1023) * 4096;
  const float* biash = bias8 + h * 4096;
#pragma unroll
  for (int qt = 0; qt < 4; ++qt) {
    f32x4 st[4];
#pragma unroll
    for (int tm = 0; tm < 4; ++tm)
      st[tm] = __builtin_amdgcn_mfma_f32_16x16x32_bf16(ka[tm], qb[qt], zf, 0, 0, 0);
    int q = qt * 16 + lrow;
    float sm = 0.f;
#pragma unroll
    for (int tm = 0; tm < 4; ++tm) {
      int kb = tm * 16 + lgrp * 4;
      float4 mb = *(const float4*)(maskw + q * 64 + kb);
      float4 bb = *(const float4*)(biash + q * 64 + kb);
#pragma unroll
      for (int r = 0; r < 4; ++r) {
        float madd = (r == 0) ? (mb.x + bb.x) : (r == 1) ? (mb.y + bb.y)
                   : (r == 2) ? (mb.z + bb.z) : (mb.w + bb.w);
        float p = __expf(st[tm][r] + madd);   // inputs bounded (|s|<~10): no max-sub
        st[tm][r] = p;
        sm += p;
      }
    }
    sm += __shfl_xor(sm, 16);
    sm += __shfl_xor(sm, 32);
    float rs = 1.0f / sm;
    uint32_t ppk[4][2];
#pragma unroll
    for (int tm = 0; tm < 4; ++tm) {
      ppk[tm][0] = pk2(st[tm][0] * rs, st[tm][1] * rs);
      ppk[tm][1] = pk2(st[tm][2] * rs, st[tm][3] * rs);
    }
    bf16x8 paf[2];
#pragma unroll
    for (int kf = 0; kf < 2; ++kf)
      paf[kf] = xpose_frag(ppk[2 * kf][0], ppk[2 * kf][1],
                           ppk[2 * kf + 1][0], ppk[2 * kf + 1][1], ad0, ad1, hi);
    f32x4 o[2] = {zf, zf};
#pragma unroll
    for (int dt = 0; dt < 2; ++dt)
#pragma unroll
      for (int kf = 0; kf < 2; ++kf) {
        bf16x8 vf = *(const bf16x8*)(ldsVt + (dt * 16 + lrow) * 72 + kf * 32 + lgrp * 8);
        o[dt] = __builtin_amdgcn_mfma_f32_16x16x32_bf16(paf[kf], vf, o[dt], 0, 0, 0);
      }
    // write O rows for this q-tile (O overlays xs; barrier above protects)
#pragma unroll
    for (int dt = 0; dt < 2; ++dt)
#pragma unroll
      for (int r = 0; r < 4; ++r)
        lds[(qt * 16 + lgrp * 4 + r) * 264 + h * 32 + dt * 16 + lrow] = (bf16_t)o[dt][r];
  }
  __syncthreads();

  // ---------- phase 5: out = O @ w_o^T + b_o (two halves: 16 acc live) ----------
  const int nb = h * 32;
  float* outw = out + (size_t)b * 16384;
#pragma unroll
  for (int half = 0; half < 2; ++half) {
    f32x4 oc[2][2];
#pragma unroll
    for (int tm = 0; tm < 2; ++tm)
#pragma unroll
      for (int tn = 0; tn < 2; ++tn) oc[tm][tn] = zf;
#pragma unroll
    for (int ks = 0; ks < 8; ++ks) {
      bf16x8 ao[2];
#pragma unroll
      for (int tm = 0; tm < 2; ++tm)
        ao[tm] = *(const bf16x8*)(lds + ((half * 2 + tm) * 16 + lrow) * 264 + ks * 32 + lgrp * 8);
      bf16x8 bw[2];
#pragma unroll
      for (int tn = 0; tn < 2; ++tn)
        bw[tn] = *(const bf16x8*)(wso + (nb + tn * 16 + lrow) * 256 + ks * 32 + lgrp * 8);
#pragma unroll
      for (int tm = 0; tm < 2; ++tm)
#pragma unroll
        for (int tn = 0; tn < 2; ++tn)
          oc[tm][tn] = __builtin_amdgcn_mfma_f32_16x16x32_bf16(ao[tm], bw[tn], oc[tm][tn], 0, 0, 0);
    }
#pragma unroll
    for (int tn = 0; tn < 2; ++tn) {
      float bov = bo[nb + tn * 16 + lrow];
#pragma unroll
      for (int tm = 0; tm < 2; ++tm)
#pragma unroll
        for (int r = 0; r < 4; ++r)
          outw[((half * 2 + tm) * 16 + lgrp * 4 + r) * 256 + nb + tn * 16 + lrow] =
              oc[tm][tn][r] + bov;
    }
  }
}

extern "C" void kernel_launch(void* const* d_in, const int* in_sizes, int n_in,
                              void* d_out, int out_size, void* d_ws, size_t ws_size,
                              hipStream_t stream) {
  const float* x    = (const float*)d_in[0];
  const float* mask = (const float*)d_in[1];
  const float* wq   = (const float*)d_in[2];
  const float* bq   = (const float*)d_in[3];
  const float* wkv  = (const float*)d_in[4];
  const float* bkv  = (const float*)d_in[5];
  const float* bt   = (const float*)d_in[6];
  const float* wo   = (const float*)d_in[7];
  const float* bo   = (const float*)d_in[8];
  const int*   rp   = (const int*)d_in[9];
  float* out = (float*)d_out;

  bf16_t* wsq  = (bf16_t*)d_ws;
  bf16_t* wskv = wsq + WS_WKV_OFF;
  bf16_t* wso  = wsq + WS_WO_OFF;
  float*  bias8 = (float*)((char*)d_ws + WS_B8_OFF);

  prep_kernel<<<512, 256, 0, stream>>>(wq, wkv, wo, bt, rp, wsq, wskv, wso, bias8);

  win_attn_kernel<<<4096, 512, 0, stream>>>(
      x, mask, bq, bkv, bo, wsq, wskv, wso, bias8, out);
}